// Round 1
// baseline (195.839 us; speedup 1.0000x reference)
//
#include <hip/hip_runtime.h>
#include <hip/hip_bf16.h>

// Problem constants (from setup_inputs): B=32, N=128, H=32, NP1=129,
// NUM_EDGES+1=1537, NUM_SPATIAL=512, MHMD=5.
#define BB 32
#define NN 128
#define HH 32
#define NP1 129
#define NE1 1537
#define MHMD 5

// ---------------------------------------------------------------------------
// Kernel 1: precompute M[d][r][k] = sum_h E[r][h] * Wd[d][h][k]
//   M: [5][1537][32] f32 (983,680 B) in d_ws
//   E: edge_encoder_w [1537][32], W: edge_dis_encoder_w flat [128*32*32]
// ---------------------------------------------------------------------------
__global__ __launch_bounds__(256) void precompute_M(const float* __restrict__ E,
                                                    const float* __restrict__ W,
                                                    float* __restrict__ M) {
    int idx = blockIdx.x * 256 + threadIdx.x;      // d*1537*32 + r*32 + k
    if (idx >= MHMD * NE1 * HH) return;
    int k = idx & 31;
    int r = (idx >> 5) % NE1;
    int d = idx / (NE1 * HH);
    const float* wd = W + d * HH * HH;             // Wd[d][h][k] = W[(d*32+h)*32+k]
    float acc = 0.f;
#pragma unroll
    for (int h = 0; h < HH; ++h)
        acc += E[r * HH + h] * wd[h * HH + k];
    M[idx] = acc;
}

// ---------------------------------------------------------------------------
// Kernel 2: borders. g[b,h,0,:] and g[b,h,1:,0] = 2*ab + t[h]
// 32*32*257 = 263,168 elements.
// ---------------------------------------------------------------------------
__global__ __launch_bounds__(256) void border_kernel(const float* __restrict__ ab,
                                                     const float* __restrict__ tvd,
                                                     float* __restrict__ out) {
    int idx = blockIdx.x * 256 + threadIdx.x;
    if (idx >= BB * HH * 257) return;
    int pos = idx % 257;
    int bh  = idx / 257;
    int h = bh & 31, b = bh >> 5;
    int r, c;
    if (pos < NP1) { r = 0; c = pos; }             // top row, all 129 cols
    else           { r = pos - 128; c = 0; }       // col 0, rows 1..128
    float v = 2.0f * ab[((size_t)b * NP1 + r) * NP1 + c] + tvd[h];
    out[(((size_t)b * HH + h) * NP1 + r) * NP1 + c] = v;
}

// ---------------------------------------------------------------------------
// Kernel 3: inner cells. One block per (b,i). 256 threads.
// Phase 1: 8 j-groups x 32 h-lanes build val[128][32] tile in LDS
//          (15 gathered M rows + spatial gather per cell).
// Phase 2: transpose through LDS (stride 33 -> conflict-free) so stores are
//          64 consecutive floats per wave.
// ---------------------------------------------------------------------------
__global__ __launch_bounds__(256) void inner_kernel(const float* __restrict__ ab,
                                                    const int* __restrict__ spatial,
                                                    const int* __restrict__ edge_input,
                                                    const float* __restrict__ M,
                                                    const float* __restrict__ spw,
                                                    float* __restrict__ out) {
    __shared__ int   s_edge[NN * 15];       // 7680 B
    __shared__ int   s_sp[NN];              //  512 B
    __shared__ float s_val[NN * 33];        // 16,896 B (padded stride 33)

    int blk = blockIdx.x;                   // b*128 + i
    int b = blk >> 7, i = blk & 127;
    int t = threadIdx.x;

    // cooperative staging of indices (int4-vectorized, contiguous)
    const int* ep = edge_input + (size_t)blk * NN * 15;   // 1920 ints, 16B-aligned
    for (int x = t; x < NN * 15 / 4; x += 256)
        ((int4*)s_edge)[x] = ((const int4*)ep)[x];
    if (t < NN) s_sp[t] = spatial[(size_t)blk * NN + t];
    __syncthreads();

    int h  = t & 31;
    int jg = t >> 5;                        // 0..7
#pragma unroll 4
    for (int jj = 0; jj < 16; ++jj) {
        int j = jg * 16 + jj;
        const int* e = &s_edge[j * 15];
        float acc = 0.f;
#pragma unroll
        for (int p = 0; p < 15; ++p) {
            int d = p / 3;
            int r = e[p];
            acc += M[((size_t)d * NE1 + r) * HH + h];     // 128B coalesced across h
        }
        int spd = s_sp[j];
        int sp1 = spd == 0 ? 1 : spd;
        sp1 = sp1 > 1 ? sp1 - 1 : sp1;
        sp1 = sp1 > MHMD ? MHMD : sp1;
        float v = spw[spd * HH + h] + acc * (1.0f / (3.0f * (float)sp1));
        s_val[j * 33 + h] = v;
    }
    __syncthreads();

    // Phase 2: out[b][h][1+i][1+j] = 2*ab[b][1+i][1+j] + val[j][h]
    int j2 = t & 127;
    int h0 = t >> 7;                        // 0 or 1
    float a2 = 2.0f * ab[((size_t)b * NP1 + (i + 1)) * NP1 + (1 + j2)];
    const size_t orow = ((size_t)b * HH) * NP1 * NP1 + (size_t)(i + 1) * NP1 + (1 + j2);
#pragma unroll 4
    for (int hh = h0; hh < HH; hh += 2) {
        out[orow + (size_t)hh * NP1 * NP1] = a2 + s_val[j2 * 33 + hh];
    }
}

// ---------------------------------------------------------------------------
// Fallback (only if ws_size cannot hold M): direct per-output computation.
// Slow but correct; never runs when ws_size >= 983,680 B.
// ---------------------------------------------------------------------------
__global__ __launch_bounds__(256) void inner_direct(const float* __restrict__ ab,
                                                    const int* __restrict__ spatial,
                                                    const int* __restrict__ edge_input,
                                                    const float* __restrict__ E,
                                                    const float* __restrict__ W,
                                                    const float* __restrict__ spw,
                                                    float* __restrict__ out) {
    long idx = (long)blockIdx.x * 256 + threadIdx.x;
    if (idx >= (long)BB * NN * NN * HH) return;
    int h = idx & 31;
    long cell = idx >> 5;                  // b*16384 + i*128 + j
    int j  = cell & 127;
    int bi = (int)(cell >> 7);
    int i  = bi & 127;
    int b  = bi >> 7;
    const int* e = edge_input + cell * 15;
    float acc = 0.f;
    for (int d = 0; d < MHMD; ++d) {
        const float* wd = W + d * HH * HH;
        int e0 = e[d * 3 + 0] * HH, e1 = e[d * 3 + 1] * HH, e2 = e[d * 3 + 2] * HH;
        for (int hp = 0; hp < HH; ++hp) {
            float eh = E[e0 + hp] + E[e1 + hp] + E[e2 + hp];
            acc += eh * wd[hp * HH + h];
        }
    }
    int spd = spatial[cell];
    int sp1 = spd == 0 ? 1 : spd;
    sp1 = sp1 > 1 ? sp1 - 1 : sp1;
    sp1 = sp1 > MHMD ? MHMD : sp1;
    float v = spw[spd * HH + h] + acc * (1.0f / (3.0f * (float)sp1));
    out[(((size_t)b * HH + h) * NP1 + (i + 1)) * NP1 + (j + 1)] =
        2.0f * ab[((size_t)b * NP1 + (i + 1)) * NP1 + (j + 1)] + v;
}

extern "C" void kernel_launch(void* const* d_in, const int* in_sizes, int n_in,
                              void* d_out, int out_size, void* d_ws, size_t ws_size,
                              hipStream_t stream) {
    const float* ab      = (const float*)d_in[0];   // attn_bias [32][129][129]
    const int*   spatial = (const int*)  d_in[1];   // spatial_pos [32][128][128]
    // d_in[2] = x (unused by reference)
    const int*   edge_in = (const int*)  d_in[3];   // edge_input [32][128][128][5][3]
    // d_in[4] = attn_edge_type (unused by reference)
    const float* E       = (const float*)d_in[5];   // edge_encoder_w [1537][32]
    const float* W       = (const float*)d_in[6];   // edge_dis_encoder_w [131072]
    const float* spw     = (const float*)d_in[7];   // spatial_pos_encoder_w [512][32]
    const float* tvd     = (const float*)d_in[8];   // graph_token_virtual_distance_w [32]
    float* out = (float*)d_out;

    // borders (independent of M)
    border_kernel<<<(BB * HH * 257 + 255) / 256, 256, 0, stream>>>(ab, tvd, out);

    const size_t M_bytes = (size_t)MHMD * NE1 * HH * sizeof(float);   // 983,680 B
    if (ws_size >= M_bytes) {
        float* M = (float*)d_ws;
        precompute_M<<<(MHMD * NE1 * HH + 255) / 256, 256, 0, stream>>>(E, W, M);
        inner_kernel<<<BB * NN, 256, 0, stream>>>(ab, spatial, edge_in, M, spw, out);
    } else {
        long total = (long)BB * NN * NN * HH;
        inner_direct<<<(unsigned)((total + 255) / 256), 256, 0, stream>>>(
            ab, spatial, edge_in, E, W, spw, out);
    }
}

// Round 3
// 164.993 us; speedup vs baseline: 1.1870x; 1.1870x over previous
//
#include <hip/hip_runtime.h>
#include <hip/hip_bf16.h>

// Problem constants: B=32, N=128, H=32, NP1=129, NUM_EDGES+1=1537, MHMD=5.
#define BB 32
#define NN 128
#define HH 32
#define NP1 129
#define NE1 1537
#define MHMD 5

// ---------------------------------------------------------------------------
// Kernel 1: precompute M[d][r][k] = sum_h E[r][h] * Wd[d][h][k]
//   M: [5][1537][32] f32 (983,680 B) in d_ws
// ---------------------------------------------------------------------------
__global__ __launch_bounds__(256) void precompute_M(const float* __restrict__ E,
                                                    const float* __restrict__ W,
                                                    float* __restrict__ M) {
    int idx = blockIdx.x * 256 + threadIdx.x;      // d*1537*32 + r*32 + k
    if (idx >= MHMD * NE1 * HH) return;
    int k = idx & 31;
    int r = (idx >> 5) % NE1;
    int d = idx / (NE1 * HH);
    const float* wd = W + d * HH * HH;
    float acc = 0.f;
#pragma unroll
    for (int h = 0; h < HH; ++h)
        acc += E[r * HH + h] * wd[h * HH + k];
    M[idx] = acc;
}

// ---------------------------------------------------------------------------
// Kernel 2: borders. g[b,h,0,:] and g[b,h,1:,0] = 2*ab + t[h]
// ---------------------------------------------------------------------------
__global__ __launch_bounds__(256) void border_kernel(const float* __restrict__ ab,
                                                     const float* __restrict__ tvd,
                                                     float* __restrict__ out) {
    int idx = blockIdx.x * 256 + threadIdx.x;
    if (idx >= BB * HH * 257) return;
    int pos = idx % 257;
    int bh  = idx / 257;
    int h = bh & 31, b = bh >> 5;
    int r, c;
    if (pos < NP1) { r = 0; c = pos; }
    else           { r = pos - 128; c = 0; }
    float v = 2.0f * ab[((size_t)b * NP1 + r) * NP1 + c] + tvd[h];
    out[(((size_t)b * HH + h) * NP1 + r) * NP1 + c] = v;
}

// ---------------------------------------------------------------------------
// Kernel 3: inner cells. One block per (b,i). 256 threads.
// Phase 1: lane = (jg=t>>3, h4=t&7); each thread owns 4 j's x 4 h's.
//          Gathers are float4 (8 lanes cover one 128B M row) -> 60 dwordx4
//          gathers/thread instead of 240 dword gathers.
// Phase 2: transpose via s_val[j][h] (stride 33, conflict-free) so stores
//          are 256B-contiguous per wave.
// ---------------------------------------------------------------------------
__global__ __launch_bounds__(256) void inner_kernel(const float* __restrict__ ab,
                                                    const int* __restrict__ spatial,
                                                    const int* __restrict__ edge_input,
                                                    const float* __restrict__ M,
                                                    const float* __restrict__ spw,
                                                    float* __restrict__ out) {
    __shared__ int   s_edge[NN * 15];       // raw edge indices, 7680 B
    __shared__ int   s_sp[NN];              // raw spatial index (for spw gather)
    __shared__ float s_mul[NN];             // 1/(3*sp1) per j
    __shared__ float s_val[NN * 33];        // padded transpose buffer

    int blk = blockIdx.x;                   // b*128 + i
    int b = blk >> 7, i = blk & 127;
    int t = threadIdx.x;

    // --- staging ---
    const int* ep = edge_input + (size_t)blk * NN * 15;   // 1920 ints
    for (int x = t; x < NN * 15 / 4; x += 256)
        ((int4*)s_edge)[x] = ((const int4*)ep)[x];
    if (t < NN) {
        int spd = spatial[(size_t)blk * NN + t];
        s_sp[t] = spd;
        int sp1 = spd == 0 ? 1 : spd;
        sp1 = sp1 > 1 ? sp1 - 1 : sp1;
        sp1 = sp1 > MHMD ? MHMD : sp1;
        s_mul[t] = 1.0f / (3.0f * (float)sp1);
    }
    __syncthreads();

    // --- phase 1: gather + accumulate ---
    const int h4 = t & 7;                   // float4 group: h = 4*h4 .. 4*h4+3
    const int jg = t >> 3;                  // 0..31, each owns j = 4*jg .. 4*jg+3
    const float4* __restrict__ M4   = (const float4*)M;
    const float4* __restrict__ spw4 = (const float4*)spw;

#pragma unroll
    for (int jj = 0; jj < 4; ++jj) {
        int j = jg * 4 + jj;
        const int* e = &s_edge[j * 15];
        float4 acc = make_float4(0.f, 0.f, 0.f, 0.f);
#pragma unroll
        for (int p = 0; p < 15; ++p) {
            // float4 index into M: (d*NE1 + r)*8 + h4, d = p/3 (compile-time)
            unsigned off = (unsigned)e[p] * 8u
                         + (unsigned)((p / 3) * NE1 * 8 + h4);
            float4 row = M4[off];
            acc.x += row.x; acc.y += row.y; acc.z += row.z; acc.w += row.w;
        }
        float  mul = s_mul[j];
        float4 sw  = spw4[(unsigned)s_sp[j] * 8u + (unsigned)h4];
        int base = j * 33 + h4 * 4;
        s_val[base + 0] = sw.x + acc.x * mul;
        s_val[base + 1] = sw.y + acc.y * mul;
        s_val[base + 2] = sw.z + acc.z * mul;
        s_val[base + 3] = sw.w + acc.w * mul;
    }
    __syncthreads();

    // --- phase 2: transpose + write ---
    int j2 = t & 127;
    int h0 = t >> 7;                        // 0 or 1
    float a2 = 2.0f * ab[((size_t)b * NP1 + (i + 1)) * NP1 + (1 + j2)];
    const size_t orow = ((size_t)b * HH) * NP1 * NP1 + (size_t)(i + 1) * NP1 + (1 + j2);
#pragma unroll 4
    for (int hh = h0; hh < HH; hh += 2) {
        out[orow + (size_t)hh * NP1 * NP1] = a2 + s_val[j2 * 33 + hh];
    }
}

// ---------------------------------------------------------------------------
// Fallback (only if ws_size cannot hold M): direct per-output computation.
// ---------------------------------------------------------------------------
__global__ __launch_bounds__(256) void inner_direct(const float* __restrict__ ab,
                                                    const int* __restrict__ spatial,
                                                    const int* __restrict__ edge_input,
                                                    const float* __restrict__ E,
                                                    const float* __restrict__ W,
                                                    const float* __restrict__ spw,
                                                    float* __restrict__ out) {
    long idx = (long)blockIdx.x * 256 + threadIdx.x;
    if (idx >= (long)BB * NN * NN * HH) return;
    int h = idx & 31;
    long cell = idx >> 5;
    int j  = cell & 127;
    int bi = (int)(cell >> 7);
    int i  = bi & 127;
    int b  = bi >> 7;
    const int* e = edge_input + cell * 15;
    float acc = 0.f;
    for (int d = 0; d < MHMD; ++d) {
        const float* wd = W + d * HH * HH;
        int e0 = e[d * 3 + 0] * HH, e1 = e[d * 3 + 1] * HH, e2 = e[d * 3 + 2] * HH;
        for (int hp = 0; hp < HH; ++hp) {
            float eh = E[e0 + hp] + E[e1 + hp] + E[e2 + hp];
            acc += eh * wd[hp * HH + h];
        }
    }
    int spd = spatial[cell];
    int sp1 = spd == 0 ? 1 : spd;
    sp1 = sp1 > 1 ? sp1 - 1 : sp1;
    sp1 = sp1 > MHMD ? MHMD : sp1;
    float v = spw[spd * HH + h] + acc / (3.0f * (float)sp1);
    out[(((size_t)b * HH + h) * NP1 + (i + 1)) * NP1 + (j + 1)] =
        2.0f * ab[((size_t)b * NP1 + (i + 1)) * NP1 + (j + 1)] + v;
}

extern "C" void kernel_launch(void* const* d_in, const int* in_sizes, int n_in,
                              void* d_out, int out_size, void* d_ws, size_t ws_size,
                              hipStream_t stream) {
    const float* ab      = (const float*)d_in[0];
    const int*   spatial = (const int*)  d_in[1];
    const int*   edge_in = (const int*)  d_in[3];
    const float* E       = (const float*)d_in[5];
    const float* W       = (const float*)d_in[6];
    const float* spw     = (const float*)d_in[7];
    const float* tvd     = (const float*)d_in[8];
    float* out = (float*)d_out;

    border_kernel<<<(BB * HH * 257 + 255) / 256, 256, 0, stream>>>(ab, tvd, out);

    const size_t M_bytes = (size_t)MHMD * NE1 * HH * sizeof(float);
    if (ws_size >= M_bytes) {
        float* M = (float*)d_ws;
        precompute_M<<<(MHMD * NE1 * HH + 255) / 256, 256, 0, stream>>>(E, W, M);
        inner_kernel<<<BB * NN, 256, 0, stream>>>(ab, spatial, edge_in, M, spw, out);
    } else {
        long total = (long)BB * NN * NN * HH;
        inner_direct<<<(unsigned)((total + 255) / 256), 256, 0, stream>>>(
            ab, spatial, edge_in, E, W, spw, out);
    }
}

// Round 4
// 161.200 us; speedup vs baseline: 1.2149x; 1.0235x over previous
//
#include <hip/hip_runtime.h>
#include <hip/hip_bf16.h>

// Problem constants: B=32, N=128, H=32, NP1=129, NUM_EDGES+1=1537, MHMD=5.
#define BB 32
#define NN 128
#define HH 32
#define NP1 129
#define NE1 1537
#define MHMD 5

// ---------------------------------------------------------------------------
// Kernel 1: precompute M[d][r][k] = sum_h E[r][h] * Wd[d][h][k], store bf16.
//   M: [5][1537][32] bf16 (491,840 B) in d_ws. Row = 64 B.
// ---------------------------------------------------------------------------
__global__ __launch_bounds__(256) void precompute_M(const float* __restrict__ E,
                                                    const float* __restrict__ W,
                                                    __hip_bfloat16* __restrict__ M) {
    int idx = blockIdx.x * 256 + threadIdx.x;      // d*1537*32 + r*32 + k
    if (idx >= MHMD * NE1 * HH) return;
    int k = idx & 31;
    int r = (idx >> 5) % NE1;
    int d = idx / (NE1 * HH);
    const float* wd = W + d * HH * HH;
    float acc = 0.f;
#pragma unroll
    for (int h = 0; h < HH; ++h)
        acc += E[r * HH + h] * wd[h * HH + k];
    M[idx] = __float2bfloat16(acc);                // RNE
}

// ---------------------------------------------------------------------------
// Kernel 2: borders. g[b,h,0,:] and g[b,h,1:,0] = 2*ab + t[h]
// ---------------------------------------------------------------------------
__global__ __launch_bounds__(256) void border_kernel(const float* __restrict__ ab,
                                                     const float* __restrict__ tvd,
                                                     float* __restrict__ out) {
    int idx = blockIdx.x * 256 + threadIdx.x;
    if (idx >= BB * HH * 257) return;
    int pos = idx % 257;
    int bh  = idx / 257;
    int h = bh & 31, b = bh >> 5;
    int r, c;
    if (pos < NP1) { r = 0; c = pos; }
    else           { r = pos - 128; c = 0; }
    float v = 2.0f * ab[((size_t)b * NP1 + r) * NP1 + c] + tvd[h];
    out[(((size_t)b * HH + h) * NP1 + r) * NP1 + c] = v;
}

// ---------------------------------------------------------------------------
// Kernel 3: inner cells. One block per (b,i). 256 threads.
// Phase 1: lane = (jg=t>>3, h4=t&7); 8 lanes cover one 64B bf16 M-row via
//          uint2 (dwordx2) gathers; 15 loads batched into regs for MLP,
//          then unpacked with shift/mask (exact bf16->f32).
// Phase 2: transpose via s_val[j][h] (stride 33) -> 256B-contig stores.
// ---------------------------------------------------------------------------
__global__ __launch_bounds__(256) void inner_kernel(const float* __restrict__ ab,
                                                    const int* __restrict__ spatial,
                                                    const int* __restrict__ edge_input,
                                                    const __hip_bfloat16* __restrict__ M,
                                                    const float* __restrict__ spw,
                                                    float* __restrict__ out) {
    __shared__ int   s_edge[NN * 15];       // raw edge indices, 7680 B
    __shared__ int   s_sp[NN];              // raw spatial index (for spw gather)
    __shared__ float s_mul[NN];             // 1/(3*sp1) per j
    __shared__ float s_val[NN * 33];        // padded transpose buffer

    int blk = blockIdx.x;                   // b*128 + i
    int b = blk >> 7, i = blk & 127;
    int t = threadIdx.x;

    // --- staging ---
    const int* ep = edge_input + (size_t)blk * NN * 15;   // 1920 ints
    for (int x = t; x < NN * 15 / 4; x += 256)
        ((int4*)s_edge)[x] = ((const int4*)ep)[x];
    if (t < NN) {
        int spd = spatial[(size_t)blk * NN + t];
        s_sp[t] = spd;
        int sp1 = spd == 0 ? 1 : spd;
        sp1 = sp1 > 1 ? sp1 - 1 : sp1;
        sp1 = sp1 > MHMD ? MHMD : sp1;
        s_mul[t] = 1.0f / (3.0f * (float)sp1);
    }
    __syncthreads();

    // --- phase 1: gather + accumulate ---
    const int h4 = t & 7;                   // 8B chunk: h = 4*h4 .. 4*h4+3
    const int jg = t >> 3;                  // 0..31, each owns j = 4*jg .. 4*jg+3
    const uint2*  __restrict__ M2   = (const uint2*)M;   // 8 chunks per 64B row
    const float4* __restrict__ spw4 = (const float4*)spw;

#pragma unroll
    for (int jj = 0; jj < 4; ++jj) {
        int j = jg * 4 + jj;
        const int* e = &s_edge[j * 15];
        // batch the 15 row-gathers into registers (MLP)
        uint2 v[15];
#pragma unroll
        for (int p = 0; p < 15; ++p) {
            unsigned off = (unsigned)e[p] * 8u
                         + (unsigned)((p / 3) * NE1 * 8 + h4);
            v[p] = M2[off];
        }
        float a0 = 0.f, a1 = 0.f, a2 = 0.f, a3 = 0.f;
#pragma unroll
        for (int p = 0; p < 15; ++p) {
            a0 += __uint_as_float(v[p].x << 16);
            a1 += __uint_as_float(v[p].x & 0xffff0000u);
            a2 += __uint_as_float(v[p].y << 16);
            a3 += __uint_as_float(v[p].y & 0xffff0000u);
        }
        float  mul = s_mul[j];
        float4 sw  = spw4[(unsigned)s_sp[j] * 8u + (unsigned)h4];
        int base = j * 33 + h4 * 4;
        s_val[base + 0] = sw.x + a0 * mul;
        s_val[base + 1] = sw.y + a1 * mul;
        s_val[base + 2] = sw.z + a2 * mul;
        s_val[base + 3] = sw.w + a3 * mul;
    }
    __syncthreads();

    // --- phase 2: transpose + write ---
    int j2 = t & 127;
    int h0 = t >> 7;                        // 0 or 1
    float a2w = 2.0f * ab[((size_t)b * NP1 + (i + 1)) * NP1 + (1 + j2)];
    const size_t orow = ((size_t)b * HH) * NP1 * NP1 + (size_t)(i + 1) * NP1 + (1 + j2);
#pragma unroll 4
    for (int hh = h0; hh < HH; hh += 2) {
        out[orow + (size_t)hh * NP1 * NP1] = a2w + s_val[j2 * 33 + hh];
    }
}

// ---------------------------------------------------------------------------
// Fallback (only if ws_size cannot hold M): direct per-output computation.
// ---------------------------------------------------------------------------
__global__ __launch_bounds__(256) void inner_direct(const float* __restrict__ ab,
                                                    const int* __restrict__ spatial,
                                                    const int* __restrict__ edge_input,
                                                    const float* __restrict__ E,
                                                    const float* __restrict__ W,
                                                    const float* __restrict__ spw,
                                                    float* __restrict__ out) {
    long idx = (long)blockIdx.x * 256 + threadIdx.x;
    if (idx >= (long)BB * NN * NN * HH) return;
    int h = idx & 31;
    long cell = idx >> 5;
    int j  = cell & 127;
    int bi = (int)(cell >> 7);
    int i  = bi & 127;
    int b  = bi >> 7;
    const int* e = edge_input + cell * 15;
    float acc = 0.f;
    for (int d = 0; d < MHMD; ++d) {
        const float* wd = W + d * HH * HH;
        int e0 = e[d * 3 + 0] * HH, e1 = e[d * 3 + 1] * HH, e2 = e[d * 3 + 2] * HH;
        for (int hp = 0; hp < HH; ++hp) {
            float eh = E[e0 + hp] + E[e1 + hp] + E[e2 + hp];
            acc += eh * wd[hp * HH + h];
        }
    }
    int spd = spatial[cell];
    int sp1 = spd == 0 ? 1 : spd;
    sp1 = sp1 > 1 ? sp1 - 1 : sp1;
    sp1 = sp1 > MHMD ? MHMD : sp1;
    float v = spw[spd * HH + h] + acc / (3.0f * (float)sp1);
    out[(((size_t)b * HH + h) * NP1 + (i + 1)) * NP1 + (j + 1)] =
        2.0f * ab[((size_t)b * NP1 + (i + 1)) * NP1 + (j + 1)] + v;
}

extern "C" void kernel_launch(void* const* d_in, const int* in_sizes, int n_in,
                              void* d_out, int out_size, void* d_ws, size_t ws_size,
                              hipStream_t stream) {
    const float* ab      = (const float*)d_in[0];
    const int*   spatial = (const int*)  d_in[1];
    const int*   edge_in = (const int*)  d_in[3];
    const float* E       = (const float*)d_in[5];
    const float* W       = (const float*)d_in[6];
    const float* spw     = (const float*)d_in[7];
    const float* tvd     = (const float*)d_in[8];
    float* out = (float*)d_out;

    border_kernel<<<(BB * HH * 257 + 255) / 256, 256, 0, stream>>>(ab, tvd, out);

    const size_t M_bytes = (size_t)MHMD * NE1 * HH * sizeof(__hip_bfloat16); // 491,840 B
    if (ws_size >= M_bytes) {
        __hip_bfloat16* M = (__hip_bfloat16*)d_ws;
        precompute_M<<<(MHMD * NE1 * HH + 255) / 256, 256, 0, stream>>>(E, W, M);
        inner_kernel<<<BB * NN, 256, 0, stream>>>(ab, spatial, edge_in, M, spw, out);
    } else {
        long total = (long)BB * NN * NN * HH;
        inner_direct<<<(unsigned)((total + 255) / 256), 256, 0, stream>>>(
            ab, spatial, edge_in, E, W, spw, out);
    }
}

// Round 6
// 153.955 us; speedup vs baseline: 1.2721x; 1.0471x over previous
//
#include <hip/hip_runtime.h>
#include <hip/hip_bf16.h>

// Problem constants: B=32, N=128, H=32, NP1=129, NUM_EDGES+1=1537, MHMD=5.
#define BB 32
#define NN 128
#define HH 32
#define NP1 129
#define NE1 1537
#define MHMD 5

// ---------------------------------------------------------------------------
// Kernel 1: precompute M[d][r][k] = sum_h E[r][h] * Wd[d][h][k], store bf16.
//   M: [5][1537][32] bf16 (491,840 B) in d_ws. Row = 64 B.
// ---------------------------------------------------------------------------
__global__ __launch_bounds__(256) void precompute_M(const float* __restrict__ E,
                                                    const float* __restrict__ W,
                                                    __hip_bfloat16* __restrict__ M) {
    int idx = blockIdx.x * 256 + threadIdx.x;      // d*1537*32 + r*32 + k
    if (idx >= MHMD * NE1 * HH) return;
    int k = idx & 31;
    int r = (idx >> 5) % NE1;
    int d = idx / (NE1 * HH);
    const float* wd = W + d * HH * HH;
    float acc = 0.f;
#pragma unroll
    for (int h = 0; h < HH; ++h)
        acc += E[r * HH + h] * wd[h * HH + k];
    M[idx] = __float2bfloat16(acc);                // RNE
}

// ---------------------------------------------------------------------------
// Kernel 2: borders. g[b,h,0,:] and g[b,h,1:,0] = 2*ab + t[h]
// ---------------------------------------------------------------------------
__global__ __launch_bounds__(256) void border_kernel(const float* __restrict__ ab,
                                                     const float* __restrict__ tvd,
                                                     float* __restrict__ out) {
    int idx = blockIdx.x * 256 + threadIdx.x;
    if (idx >= BB * HH * 257) return;
    int pos = idx % 257;
    int bh  = idx / 257;
    int h = bh & 31, b = bh >> 5;
    int r, c;
    if (pos < NP1) { r = 0; c = pos; }
    else           { r = pos - 128; c = 0; }
    float v = 2.0f * ab[((size_t)b * NP1 + r) * NP1 + c] + tvd[h];
    out[(((size_t)b * HH + h) * NP1 + r) * NP1 + c] = v;
}

// ---------------------------------------------------------------------------
// Kernel 3: inner cells. One block per (b,i). 256 threads.
// Phase 1: lane = (jg=t>>2, h8=t&3); 4 lanes cover one 64B bf16 M-row via
//          uint4 (dwordx4) gathers -> 16 rows per wave-instruction, 30
//          scattered loads per thread (was 60). Cost model from r3/r4 A/B:
//          gather cost is per-instruction (per-lane-address), not per-byte.
// Phase 2: transpose via s_val[j][h] (stride 33) -> 256B-contig stores.
// ---------------------------------------------------------------------------
__global__ __launch_bounds__(256) void inner_kernel(const float* __restrict__ ab,
                                                    const int* __restrict__ spatial,
                                                    const int* __restrict__ edge_input,
                                                    const __hip_bfloat16* __restrict__ M,
                                                    const float* __restrict__ spw,
                                                    float* __restrict__ out) {
    __shared__ int   s_edge[NN * 15];       // raw edge indices, 7680 B
    __shared__ int   s_sp[NN];              // raw spatial index (for spw gather)
    __shared__ float s_mul[NN];             // 1/(3*sp1) per j
    __shared__ float s_val[NN * 33];        // padded transpose buffer

    int blk = blockIdx.x;                   // b*128 + i
    int b = blk >> 7, i = blk & 127;
    int t = threadIdx.x;

    // --- staging ---
    const int* ep = edge_input + (size_t)blk * NN * 15;   // 1920 ints
    for (int x = t; x < NN * 15 / 4; x += 256)
        ((int4*)s_edge)[x] = ((const int4*)ep)[x];
    if (t < NN) {
        int spd = spatial[(size_t)blk * NN + t];
        s_sp[t] = spd;
        int sp1 = spd == 0 ? 1 : spd;
        sp1 = sp1 > 1 ? sp1 - 1 : sp1;
        sp1 = sp1 > MHMD ? MHMD : sp1;
        s_mul[t] = 1.0f / (3.0f * (float)sp1);
    }
    __syncthreads();

    // --- phase 1: gather + accumulate ---
    const int h8 = t & 3;                   // 16B chunk: h = 8*h8 .. 8*h8+7
    const int jg = t >> 2;                  // 0..63, each owns j = 2*jg, 2*jg+1
    const uint4*  __restrict__ M4   = (const uint4*)M;   // 4 chunks per 64B row
    const float4* __restrict__ spw4 = (const float4*)spw;

#pragma unroll
    for (int jj = 0; jj < 2; ++jj) {
        int j = jg * 2 + jj;
        const int* e = &s_edge[j * 15];
        // batch the 15 row-gathers into registers (MLP)
        uint4 v[15];
#pragma unroll
        for (int p = 0; p < 15; ++p) {
            unsigned off = (unsigned)e[p] * 4u
                         + (unsigned)((p / 3) * NE1 * 4 + h8);
            v[p] = M4[off];
        }
        float a0 = 0.f, a1 = 0.f, a2 = 0.f, a3 = 0.f;
        float a4 = 0.f, a5 = 0.f, a6 = 0.f, a7 = 0.f;
#pragma unroll
        for (int p = 0; p < 15; ++p) {
            a0 += __uint_as_float(v[p].x << 16);
            a1 += __uint_as_float(v[p].x & 0xffff0000u);
            a2 += __uint_as_float(v[p].y << 16);
            a3 += __uint_as_float(v[p].y & 0xffff0000u);
            a4 += __uint_as_float(v[p].z << 16);
            a5 += __uint_as_float(v[p].z & 0xffff0000u);
            a6 += __uint_as_float(v[p].w << 16);
            a7 += __uint_as_float(v[p].w & 0xffff0000u);
        }
        float  mul = s_mul[j];
        unsigned sb = (unsigned)s_sp[j] * 8u + (unsigned)(h8 * 2);
        float4 sw0 = spw4[sb];
        float4 sw1 = spw4[sb + 1u];
        int base = j * 33 + h8 * 8;
        s_val[base + 0] = sw0.x + a0 * mul;
        s_val[base + 1] = sw0.y + a1 * mul;
        s_val[base + 2] = sw0.z + a2 * mul;
        s_val[base + 3] = sw0.w + a3 * mul;
        s_val[base + 4] = sw1.x + a4 * mul;
        s_val[base + 5] = sw1.y + a5 * mul;
        s_val[base + 6] = sw1.z + a6 * mul;
        s_val[base + 7] = sw1.w + a7 * mul;
    }
    __syncthreads();

    // --- phase 2: transpose + write ---
    int j2 = t & 127;
    int h0 = t >> 7;                        // 0 or 1
    float a2w = 2.0f * ab[((size_t)b * NP1 + (i + 1)) * NP1 + (1 + j2)];
    const size_t orow = ((size_t)b * HH) * NP1 * NP1 + (size_t)(i + 1) * NP1 + (1 + j2);
#pragma unroll 4
    for (int hh = h0; hh < HH; hh += 2) {
        out[orow + (size_t)hh * NP1 * NP1] = a2w + s_val[j2 * 33 + hh];
    }
}

// ---------------------------------------------------------------------------
// Fallback (only if ws_size cannot hold M): direct per-output computation.
// ---------------------------------------------------------------------------
__global__ __launch_bounds__(256) void inner_direct(const float* __restrict__ ab,
                                                    const int* __restrict__ spatial,
                                                    const int* __restrict__ edge_input,
                                                    const float* __restrict__ E,
                                                    const float* __restrict__ W,
                                                    const float* __restrict__ spw,
                                                    float* __restrict__ out) {
    long idx = (long)blockIdx.x * 256 + threadIdx.x;
    if (idx >= (long)BB * NN * NN * HH) return;
    int h = idx & 31;
    long cell = idx >> 5;
    int j  = cell & 127;
    int bi = (int)(cell >> 7);
    int i  = bi & 127;
    int b  = bi >> 7;
    const int* e = edge_input + cell * 15;
    float acc = 0.f;
    for (int d = 0; d < MHMD; ++d) {
        const float* wd = W + d * HH * HH;
        int e0 = e[d * 3 + 0] * HH, e1 = e[d * 3 + 1] * HH, e2 = e[d * 3 + 2] * HH;
        for (int hp = 0; hp < HH; ++hp) {
            float eh = E[e0 + hp] + E[e1 + hp] + E[e2 + hp];
            acc += eh * wd[hp * HH + h];
        }
    }
    int spd = spatial[cell];
    int sp1 = spd == 0 ? 1 : spd;
    sp1 = sp1 > 1 ? sp1 - 1 : sp1;
    sp1 = sp1 > MHMD ? MHMD : sp1;
    float v = spw[spd * HH + h] + acc / (3.0f * (float)sp1);
    out[(((size_t)b * HH + h) * NP1 + (i + 1)) * NP1 + (j + 1)] =
        2.0f * ab[((size_t)b * NP1 + (i + 1)) * NP1 + (j + 1)] + v;
}

extern "C" void kernel_launch(void* const* d_in, const int* in_sizes, int n_in,
                              void* d_out, int out_size, void* d_ws, size_t ws_size,
                              hipStream_t stream) {
    const float* ab      = (const float*)d_in[0];
    const int*   spatial = (const int*)  d_in[1];
    const int*   edge_in = (const int*)  d_in[3];
    const float* E       = (const float*)d_in[5];
    const float* W       = (const float*)d_in[6];
    const float* spw     = (const float*)d_in[7];
    const float* tvd     = (const float*)d_in[8];
    float* out = (float*)d_out;

    border_kernel<<<(BB * HH * 257 + 255) / 256, 256, 0, stream>>>(ab, tvd, out);

    const size_t M_bytes = (size_t)MHMD * NE1 * HH * sizeof(__hip_bfloat16); // 491,840 B
    if (ws_size >= M_bytes) {
        __hip_bfloat16* M = (__hip_bfloat16*)d_ws;
        precompute_M<<<(MHMD * NE1 * HH + 255) / 256, 256, 0, stream>>>(E, W, M);
        inner_kernel<<<BB * NN, 256, 0, stream>>>(ab, spatial, edge_in, M, spw, out);
    } else {
        long total = (long)BB * NN * NN * HH;
        inner_direct<<<(unsigned)((total + 255) / 256), 256, 0, stream>>>(
            ab, spatial, edge_in, E, W, spw, out);
    }
}